// Round 18
// baseline (3601.049 us; speedup 1.0000x reference)
//
#include <hip/hip_runtime.h>
#include <hip/hip_bf16.h>
#include <cmath>

// Problem dims (fixed)
#define B_ 64
#define L_ 197
#define D_ 768
#define H_ 12
#define NL_ 12
#define F_ 3072
#define M_ (B_*L_)          // 12608
#define MPAD_ 12672         // 128*99
#define NPREP_ 1731

typedef __bf16 bf16_t;
typedef __bf16 bf16x8 __attribute__((ext_vector_type(8)));
typedef __bf16 bf16x4 __attribute__((ext_vector_type(4)));
typedef float  f32x4  __attribute__((ext_vector_type(4)));

#define GPTR(p) ((const __attribute__((address_space(1))) void*)(p))
#define LPTR(p) ((__attribute__((address_space(3))) void*)(p))

__device__ __forceinline__ float gelu_f(float x) {
    return 0.5f * x * (1.f + erff(x * 0.70710678118654752440f));
}

struct PrepArgs {
    const float *Wq, *Wk, *Wv, *Wo, *W1, *W2, *bq, *bk, *bv;
    bf16_t *wqkvT, *woT, *w1T, *w2T;
    float *bqkv;
};

// prep body: 1731 blocks — 3 bias + 576 (Wq,Wk,Wv,Wo) + 576 (W1) + 576 (W2).
// PAD=67 (odd): transpose-read bank stride 12 mod 32.
__device__ __forceinline__ void prep_body(int bidx, int tid, const PrepArgs& pa, void* lds) {
    if (bidx < 3) {
        int i = bidx * 256 + tid;
        if (i < D_) {
            pa.bqkv[i] = pa.bq[i]; pa.bqkv[D_ + i] = pa.bk[i]; pa.bqkv[2*D_ + i] = pa.bv[i];
        }
        return;
    }
    int t = bidx - 3;
    const float* W; bf16_t* BT; int K, N;
    if (t < 576) {
        int seg = t / 144; t -= seg * 144;
        K = D_; N = D_;
        W  = (seg == 0 ? pa.Wq : seg == 1 ? pa.Wk : seg == 2 ? pa.Wv : pa.Wo);
        BT = (seg == 3 ? pa.woT : pa.wqkvT + (size_t)seg * 768 * D_);
    } else if (t < 1152) { t -= 576;  W = pa.W1; BT = pa.w1T; K = D_; N = F_; }
    else                 { t -= 1152; W = pa.W2; BT = pa.w2T; K = F_; N = D_; }
    const int kt = K / 64;
    const int k0 = (t % kt) * 64, n0 = (t / kt) * 64;

    bf16_t (*s)[67] = (bf16_t(*)[67])lds;
    int kr = tid >> 4, nc = (tid & 15) * 4;
    #pragma unroll
    for (int i = 0; i < 4; ++i) {
        float4 v = *(const float4*)(W + (size_t)(k0 + kr + i*16) * N + n0 + nc);
        s[kr + i*16][nc]     = (bf16_t)v.x;
        s[kr + i*16][nc + 1] = (bf16_t)v.y;
        s[kr + i*16][nc + 2] = (bf16_t)v.z;
        s[kr + i*16][nc + 3] = (bf16_t)v.w;
    }
    __syncthreads();
    int nr = tid >> 3, kc = (tid & 7) * 8;
    #pragma unroll
    for (int i = 0; i < 2; ++i) {
        bf16x8 o;
        #pragma unroll
        for (int j = 0; j < 8; ++j) o[j] = s[kc + j][nr + i*32];
        *(bf16x8*)(BT + (size_t)(n0 + nr + i*32) * K + k0 + kc) = o;
    }
}

// ---------------- elementwise: h = bf16(x + pos), with layer-0 prep piggyback ----------
__global__ __launch_bounds__(256) void k_addpos_prep(const float4* __restrict__ x,
                                                     const float4* __restrict__ pos,
                                                     bf16x4* __restrict__ h,
                                                     int n4, int ld4, int nblk_add,
                                                     PrepArgs pa) {
    __shared__ bf16_t s[64][67];
    if ((int)blockIdx.x >= nblk_add) {
        prep_body((int)blockIdx.x - nblk_add, threadIdx.x, pa, (void*)s);
        return;
    }
    int i = blockIdx.x * 256 + threadIdx.x;
    if (i < n4) {
        float4 a = x[i];
        float4 p = pos[i % ld4];
        bf16x4 o;
        o[0] = (bf16_t)(a.x + p.x); o[1] = (bf16_t)(a.y + p.y);
        o[2] = (bf16_t)(a.z + p.z); o[3] = (bf16_t)(a.w + p.w);
        h[i] = o;
    }
}

// ---------------- LayerNorm: one wave per row, bf16 input ----------------
template<bool BF16OUT>
__global__ __launch_bounds__(256) void k_ln(const bf16_t* __restrict__ x,
                                            const float* __restrict__ g,
                                            const float* __restrict__ bsh,
                                            void* __restrict__ out) {
    int wid = threadIdx.x >> 6, lane = threadIdx.x & 63;
    size_t row = (size_t)blockIdx.x * 4 + wid;
    const bf16x4* xr = (const bf16x4*)(x + row * D_);
    float vv[12];
    float s = 0.f, sq = 0.f;
    #pragma unroll
    for (int i = 0; i < 3; ++i) {
        bf16x4 v4 = xr[i*64 + lane];
        #pragma unroll
        for (int j = 0; j < 4; ++j) {
            float f = (float)v4[j];
            vv[i*4 + j] = f; s += f; sq += f*f;
        }
    }
    #pragma unroll
    for (int o = 1; o < 64; o <<= 1) { s += __shfl_xor(s, o); sq += __shfl_xor(sq, o); }
    float mean = s * (1.f/768.f);
    float var  = sq * (1.f/768.f) - mean*mean;
    float rstd = rsqrtf(var + 1e-6f);
    const float4* g4 = (const float4*)g;
    const float4* b4 = (const float4*)bsh;
    #pragma unroll
    for (int i = 0; i < 3; ++i) {
        float4 gg = g4[i*64 + lane], bb = b4[i*64 + lane];
        float r0 = (vv[i*4+0] - mean)*rstd*gg.x + bb.x;
        float r1 = (vv[i*4+1] - mean)*rstd*gg.y + bb.y;
        float r2 = (vv[i*4+2] - mean)*rstd*gg.z + bb.z;
        float r3 = (vv[i*4+3] - mean)*rstd*gg.w + bb.w;
        if (BF16OUT) {
            bf16x4 o4; o4[0]=(bf16_t)r0; o4[1]=(bf16_t)r1; o4[2]=(bf16_t)r2; o4[3]=(bf16_t)r3;
            ((bf16x4*)((bf16_t*)out + row * D_))[i*64 + lane] = o4;
        } else {
            float4 r; r.x=r0; r.y=r1; r.z=r2; r.w=r3;
            ((float4*)out)[row * (D_/4) + i*64 + lane] = r;
        }
    }
}

// ---------------- GEMM 128x128 (m97-pure, 4 blocks/CU) + optional prep piggyback -------
// single-buffer LDS, 2x __syncthreads, no fences. T2 swizzle, XCD swizzle (over nwg).
// EPI 0: bias->bf16 wide.  EPI 1: +gelu wide.  EPI 2: bias+resid->bf16 wide f32-LDS.
// PREP: blocks [nwg, nwg+NPREP_) run prep_body for the NEXT layer's weights.
template<int EPI, bool PREP>
__global__ __launch_bounds__(256, 4) void k_gemm_bt(
        const bf16_t* __restrict__ A, const bf16_t* __restrict__ BT,
        const float* __restrict__ bias, const bf16_t* __restrict__ resid,
        void* __restrict__ Cout, int K, int N, int NB, int nwg, PrepArgs pa) {
    __shared__ bf16_t LDS_[2][128 * 64];   // 32KB total, contiguous
    bf16_t* As = LDS_[0];
    bf16_t* Bs = LDS_[1];

    const int tid = threadIdx.x, lane = tid & 63, wid = tid >> 6;

    if (PREP && (int)blockIdx.x >= nwg) {
        prep_body((int)blockIdx.x - nwg, tid, pa, (void*)LDS_);
        return;
    }

    const int g = lane >> 4, fr = lane & 15;
    const int wm = (wid >> 1) * 64, wn = (wid & 1) * 64;

    int orig = (int)blockIdx.x;
    int qq = nwg >> 3, rr = nwg & 7;
    int xcd = orig & 7, idx = orig >> 3;
    int wg = (xcd < rr ? xcd * (qq + 1) : rr * (qq + 1) + (xcd - rr) * qq) + idx;
    int bx = wg / NB, by = wg - bx * NB;
    const int gm0 = bx * 128, gn0 = by * 128;

    const int srl = lane >> 3;
    const int sc = ((lane & 7) ^ srl) * 8;

    f32x4 acc[4][4];
    #pragma unroll
    for (int i = 0; i < 4; ++i)
        #pragma unroll
        for (int j = 0; j < 4; ++j) acc[i][j] = (f32x4){0.f, 0.f, 0.f, 0.f};

    const bf16_t* a_src = A  + (size_t)(gm0 + wid * 32 + srl) * K + sc;
    const bf16_t* b_src = BT + (size_t)(gn0 + wid * 32 + srl) * K + sc;

    const int NT = K >> 6;
    for (int t = 0; t < NT; ++t) {
        const int k0 = t * 64;
        __syncthreads();
        #pragma unroll
        for (int i = 0; i < 4; ++i) {
            __builtin_amdgcn_global_load_lds(GPTR(a_src + (size_t)(i * 8) * K + k0),
                                             LPTR(&As[(wid * 32 + i * 8) * 64]), 16, 0, 0);
            __builtin_amdgcn_global_load_lds(GPTR(b_src + (size_t)(i * 8) * K + k0),
                                             LPTR(&Bs[(wid * 32 + i * 8) * 64]), 16, 0, 0);
        }
        __syncthreads();

        bf16x8 af[4][2], bf[4][2];
        #pragma unroll
        for (int mi = 0; mi < 4; ++mi) {
            const int row = wm + mi * 16 + fr;
            #pragma unroll
            for (int kc = 0; kc < 2; ++kc)
                af[mi][kc] = *(const bf16x8*)&As[row * 64 + (((kc * 4 + g) ^ (row & 7)) * 8)];
        }
        #pragma unroll
        for (int ni = 0; ni < 4; ++ni) {
            const int row = wn + ni * 16 + fr;
            #pragma unroll
            for (int kc = 0; kc < 2; ++kc)
                bf[ni][kc] = *(const bf16x8*)&Bs[row * 64 + (((kc * 4 + g) ^ (row & 7)) * 8)];
        }
        #pragma unroll
        for (int kc = 0; kc < 2; ++kc)
            #pragma unroll
            for (int mi = 0; mi < 4; ++mi)
                #pragma unroll
                for (int ni = 0; ni < 4; ++ni)
                    acc[mi][ni] = __builtin_amdgcn_mfma_f32_16x16x32_bf16(
                        af[mi][kc], bf[ni][kc], acc[mi][ni], 0, 0, 0);
    }

    if (EPI == 2) {
        // wide epilogue, f32 precision: two halves of 64 rows through f32 LDS [64][128].
        float* Cf = (float*)&LDS_[0][0];     // 32 KB
        #pragma unroll
        for (int h = 0; h < 2; ++h) {
            __syncthreads();
            if ((wid >> 1) == h) {
                #pragma unroll
                for (int mi = 0; mi < 4; ++mi)
                    #pragma unroll
                    for (int ni = 0; ni < 4; ++ni) {
                        const int c = wn + ni * 16 + fr;
                        const float bval = bias[gn0 + c];
                        #pragma unroll
                        for (int v = 0; v < 4; ++v) {
                            const int rl = mi * 16 + g * 4 + v;   // 0..63
                            Cf[rl * 128 + (((c >> 2) ^ (rl & 7)) << 2) + (c & 3)] =
                                acc[mi][ni][v] + bval;
                        }
                    }
            }
            __syncthreads();
            #pragma unroll
            for (int pass = 0; pass < 4; ++pass) {
                const int rl = pass * 16 + (tid >> 4);
                const int lc0 = (tid & 15) * 2;
                const int s2 = rl & 7;
                f32x4 lo = *(const f32x4*)&Cf[rl * 128 + ((lc0 ^ s2) << 2)];
                f32x4 hi = *(const f32x4*)&Cf[rl * 128 + (((lc0 + 1) ^ s2) << 2)];
                const int grow = gm0 + h * 64 + rl;
                if (grow < M_) {
                    const size_t base = (size_t)grow * N + gn0 + (tid & 15) * 8;
                    bf16x8 res = *(const bf16x8*)(resid + base);
                    bf16x8 o;
                    o[0] = (bf16_t)(lo[0] + (float)res[0]);
                    o[1] = (bf16_t)(lo[1] + (float)res[1]);
                    o[2] = (bf16_t)(lo[2] + (float)res[2]);
                    o[3] = (bf16_t)(lo[3] + (float)res[3]);
                    o[4] = (bf16_t)(hi[0] + (float)res[4]);
                    o[5] = (bf16_t)(hi[1] + (float)res[5]);
                    o[6] = (bf16_t)(hi[2] + (float)res[6]);
                    o[7] = (bf16_t)(hi[3] + (float)res[7]);
                    *(bf16x8*)((bf16_t*)Cout + base) = o;
                }
            }
        }
    } else {
        // wide epilogue: bf16 LDS transpose (32KB = [128][128] bf16, chunk-XOR swizzled)
        __syncthreads();
        bf16_t* Cs = &LDS_[0][0];
        #pragma unroll
        for (int mi = 0; mi < 4; ++mi)
            #pragma unroll
            for (int ni = 0; ni < 4; ++ni) {
                const int col = wn + ni * 16 + fr;
                const float bval = bias[gn0 + col];
                const int ch = col >> 3, co = col & 7;
                #pragma unroll
                for (int v = 0; v < 4; ++v) {
                    const int row = wm + mi * 16 + g * 4 + v;
                    float val = acc[mi][ni][v] + bval;
                    if (EPI == 1) val = gelu_f(val);
                    Cs[row * 128 + ((ch ^ (row & 7)) << 3) + co] = (bf16_t)val;
                }
            }
        __syncthreads();
        #pragma unroll
        for (int p = 0; p < 8; ++p) {
            const int row = p * 16 + (tid >> 4);
            const int ch  = tid & 15;
            const int grow = gm0 + row;
            bf16x8 cv = *(const bf16x8*)&Cs[row * 128 + ((ch ^ (row & 7)) << 3)];
            if (grow < M_)
                *(bf16x8*)((bf16_t*)Cout + (size_t)grow * N + gn0 + ch * 8) = cv;
        }
    }
}

// ---------------- Attention: one block per (b,h), full-row softmax ----------------
__global__ __launch_bounds__(256) void k_attn(const bf16_t* __restrict__ qkv,
                                              bf16_t* __restrict__ out) {
    __shared__ bf16_t VT[64][232];
    __shared__ bf16_t P[4][16][232];
    int tid = threadIdx.x, lane = tid & 63, wid = tid >> 6;
    int b = blockIdx.x / H_, hh = blockIdx.x % H_;
    const size_t base = (size_t)b * L_ * 2304 + hh * 64;

    for (int r = tid >> 3; r < L_; r += 32) {
        int cg = (tid & 7) * 8;
        bf16x8 vv = *(const bf16x8*)(qkv + base + (size_t)r * 2304 + 1536 + cg);
        #pragma unroll
        for (int j = 0; j < 8; ++j) VT[cg + j][r] = vv[j];
    }
    for (int i = tid; i < 64 * 35; i += 256) VT[i / 35][197 + i % 35] = (bf16_t)0.f;
    {
        int r = lane & 15, c0 = 208 + (lane >> 4) * 4;
        #pragma unroll
        for (int j = 0; j < 4; ++j) P[wid][r][c0 + j] = (bf16_t)0.f;
    }
    __syncthreads();

    for (int s = wid; s < 13; s += 4) {
        int q0 = s * 16;
        int qr = q0 + (lane & 15); if (qr > L_ - 1) qr = L_ - 1;
        bf16x8 qf[2];
        #pragma unroll
        for (int kk = 0; kk < 2; ++kk)
            qf[kk] = *(const bf16x8*)(qkv + base + (size_t)qr * 2304 + kk * 32 + (lane >> 4) * 8);

        f32x4 sacc[13];
        #pragma unroll
        for (int nb = 0; nb < 13; ++nb) { f32x4 z = {0.f,0.f,0.f,0.f}; sacc[nb] = z; }
        #pragma unroll
        for (int nb = 0; nb < 13; ++nb) {
            int lk = nb * 16 + (lane & 15); if (lk > L_ - 1) lk = L_ - 1;
            #pragma unroll
            for (int kk = 0; kk < 2; ++kk) {
                bf16x8 kf = *(const bf16x8*)(qkv + base + (size_t)lk * 2304 + D_ + kk * 32 + (lane >> 4) * 8);
                sacc[nb] = __builtin_amdgcn_mfma_f32_16x16x32_bf16(qf[kk], kf, sacc[nb], 0, 0, 0);
            }
        }

        float mx[4] = {-1e30f, -1e30f, -1e30f, -1e30f};
        float pv[13][4];
        #pragma unroll
        for (int nb = 0; nb < 13; ++nb) {
            bool valid = (nb * 16 + (lane & 15)) < L_;
            #pragma unroll
            for (int v = 0; v < 4; ++v) {
                float sv = valid ? sacc[nb][v] * 0.125f : -1e30f;
                pv[nb][v] = sv;
                mx[v] = fmaxf(mx[v], sv);
            }
        }
        #pragma unroll
        for (int o = 1; o < 16; o <<= 1) {
            #pragma unroll
            for (int v = 0; v < 4; ++v) mx[v] = fmaxf(mx[v], __shfl_xor(mx[v], o));
        }
        float sum[4] = {0.f, 0.f, 0.f, 0.f};
        #pragma unroll
        for (int nb = 0; nb < 13; ++nb) {
            bool valid = (nb * 16 + (lane & 15)) < L_;
            #pragma unroll
            for (int v = 0; v < 4; ++v) {
                float e2 = valid ? __expf(pv[nb][v] - mx[v]) : 0.f;
                pv[nb][v] = e2; sum[v] += e2;
            }
        }
        #pragma unroll
        for (int o = 1; o < 16; o <<= 1) {
            #pragma unroll
            for (int v = 0; v < 4; ++v) sum[v] += __shfl_xor(sum[v], o);
        }

        #pragma unroll
        for (int nb = 0; nb < 13; ++nb)
            #pragma unroll
            for (int v = 0; v < 4; ++v)
                P[wid][(lane >> 4) * 4 + v][nb * 16 + (lane & 15)] = (bf16_t)pv[nb][v];
        asm volatile("s_waitcnt lgkmcnt(0)" ::: "memory");

        f32x4 oacc[4];
        #pragma unroll
        for (int nb = 0; nb < 4; ++nb) { f32x4 z = {0.f,0.f,0.f,0.f}; oacc[nb] = z; }
        #pragma unroll
        for (int kk = 0; kk < 7; ++kk) {
            bf16x8 pf = *(const bf16x8*)&P[wid][lane & 15][kk * 32 + (lane >> 4) * 8];
            #pragma unroll
            for (int nb = 0; nb < 4; ++nb) {
                bf16x8 vf = *(const bf16x8*)&VT[nb * 16 + (lane & 15)][kk * 32 + (lane >> 4) * 8];
                oacc[nb] = __builtin_amdgcn_mfma_f32_16x16x32_bf16(pf, vf, oacc[nb], 0, 0, 0);
            }
        }

        float rs[4];
        #pragma unroll
        for (int v = 0; v < 4; ++v) rs[v] = 1.f / sum[v];
        #pragma unroll
        for (int nb = 0; nb < 4; ++nb)
            #pragma unroll
            for (int v = 0; v < 4; ++v) {
                int r = q0 + (lane >> 4) * 4 + v;
                if (r < L_)
                    out[((size_t)b * L_ + r) * D_ + hh * 64 + nb * 16 + (lane & 15)] =
                        (bf16_t)(oacc[nb][v] * rs[v]);
            }
    }
}

// ---------------- host orchestration ----------------
extern "C" void kernel_launch(void* const* d_in, const int* in_sizes, int n_in,
                              void* d_out, int out_size, void* d_ws, size_t ws_size,
                              hipStream_t stream) {
    const float* x     = (const float*)d_in[0];
    const float* pos   = (const float*)d_in[1];
    const float* ln1_g = (const float*)d_in[2];
    const float* ln1_b = (const float*)d_in[3];
    const float* Wq    = (const float*)d_in[4];
    const float* bq    = (const float*)d_in[5];
    const float* Wk    = (const float*)d_in[6];
    const float* bk    = (const float*)d_in[7];
    const float* Wv    = (const float*)d_in[8];
    const float* bv    = (const float*)d_in[9];
    const float* Wo    = (const float*)d_in[10];
    const float* bo    = (const float*)d_in[11];
    const float* ln2_g = (const float*)d_in[12];
    const float* ln2_b = (const float*)d_in[13];
    const float* W1    = (const float*)d_in[14];
    const float* b1    = (const float*)d_in[15];
    const float* W2    = (const float*)d_in[16];
    const float* b2    = (const float*)d_in[17];
    const float* lnf_g = (const float*)d_in[18];
    const float* lnf_b = (const float*)d_in[19];

    char* wsp = (char*)d_ws;
    size_t off = 0;
    auto alloc = [&](size_t bytes) -> void* {
        void* r = wsp + off;
        off += (bytes + 255) & ~(size_t)255;
        return r;
    };
    bf16_t* h     = (bf16_t*)alloc((size_t)M_ * D_ * 2);
    bf16_t* y     = (bf16_t*)alloc((size_t)MPAD_ * D_ * 2);
    bf16_t* qkv   = (bf16_t*)alloc((size_t)M_ * 2304 * 2);
    bf16_t* attn  = (bf16_t*)alloc((size_t)MPAD_ * D_ * 2);
    bf16_t* u     = (bf16_t*)alloc((size_t)MPAD_ * F_ * 2);
    bf16_t* wqkvT[2]; bf16_t* woT[2]; bf16_t* w1T[2]; bf16_t* w2T[2]; float* bqkv[2];
    for (int p = 0; p < 2; ++p) {
        wqkvT[p] = (bf16_t*)alloc((size_t)2304 * D_ * 2);
        woT[p]   = (bf16_t*)alloc((size_t)D_ * D_ * 2);
        w1T[p]   = (bf16_t*)alloc((size_t)F_ * D_ * 2);
        w2T[p]   = (bf16_t*)alloc((size_t)D_ * F_ * 2);
        bqkv[p]  = (float*) alloc(2304 * 4);
    }
    (void)ws_size; (void)in_sizes; (void)n_in; (void)out_size;

    auto mkprep = [&](int l) -> PrepArgs {
        int p = l & 1;
        PrepArgs pa;
        pa.Wq = Wq + (size_t)l * D_ * D_; pa.Wk = Wk + (size_t)l * D_ * D_;
        pa.Wv = Wv + (size_t)l * D_ * D_; pa.Wo = Wo + (size_t)l * D_ * D_;
        pa.W1 = W1 + (size_t)l * D_ * F_; pa.W2 = W2 + (size_t)l * F_ * D_;
        pa.bq = bq + l * D_; pa.bk = bk + l * D_; pa.bv = bv + l * D_;
        pa.wqkvT = wqkvT[p]; pa.woT = woT[p]; pa.w1T = w1T[p]; pa.w2T = w2T[p];
        pa.bqkv = bqkv[p];
        return pa;
    };
    PrepArgs nopa = {};

    {
        int n4 = M_ * D_ / 4;
        int nblk = n4 / 256;     // 9456 exactly
        k_addpos_prep<<<nblk + NPREP_, 256, 0, stream>>>(
            (const float4*)x, (const float4*)pos, (bf16x4*)h, n4, L_ * D_ / 4,
            nblk, mkprep(0));
    }

    for (int l = 0; l < NL_; ++l) {
        const int p = l & 1;
        k_ln<true><<<M_ / 4, 256, 0, stream>>>(h, ln1_g + l * D_, ln1_b + l * D_, y);
        k_gemm_bt<0, false><<<dim3(99 * 18), 256, 0, stream>>>(
            y, wqkvT[p], bqkv[p], nullptr, qkv, D_, 2304, 18, 99 * 18, nopa);
        k_attn<<<B_ * H_, 256, 0, stream>>>(qkv, attn);
        k_gemm_bt<2, false><<<dim3(99 * 6), 256, 0, stream>>>(
            attn, woT[p], bo + l * D_, h, h, D_, D_, 6, 99 * 6, nopa);
        k_ln<true><<<M_ / 4, 256, 0, stream>>>(h, ln2_g + l * D_, ln2_b + l * D_, y);
        if (l + 1 < NL_) {
            k_gemm_bt<1, true><<<dim3(99 * 24 + NPREP_), 256, 0, stream>>>(
                y, w1T[p], b1 + (size_t)l * F_, nullptr, u, D_, F_, 24, 99 * 24, mkprep(l + 1));
        } else {
            k_gemm_bt<1, false><<<dim3(99 * 24), 256, 0, stream>>>(
                y, w1T[p], b1 + (size_t)l * F_, nullptr, u, D_, F_, 24, 99 * 24, nopa);
        }
        k_gemm_bt<2, false><<<dim3(99 * 6), 256, 0, stream>>>(
            u, w2T[p], b2 + l * D_, h, h, F_, D_, 6, 99 * 6, nopa);
    }
    k_ln<false><<<M_ / 4, 256, 0, stream>>>(h, lnf_g, lnf_b, d_out);
}

// Round 19
// 3587.500 us; speedup vs baseline: 1.0038x; 1.0038x over previous
//
#include <hip/hip_runtime.h>
#include <hip/hip_bf16.h>
#include <cmath>

// Problem dims (fixed)
#define B_ 64
#define L_ 197
#define D_ 768
#define H_ 12
#define NL_ 12
#define F_ 3072
#define M_ (B_*L_)          // 12608
#define MPAD_ 12672         // 128*99
#define NPREP_ 1731

typedef __bf16 bf16_t;
typedef __bf16 bf16x8 __attribute__((ext_vector_type(8)));
typedef __bf16 bf16x4 __attribute__((ext_vector_type(4)));
typedef float  f32x4  __attribute__((ext_vector_type(4)));

#define GPTR(p) ((const __attribute__((address_space(1))) void*)(p))
#define LPTR(p) ((__attribute__((address_space(3))) void*)(p))

__device__ __forceinline__ float gelu_f(float x) {
    return 0.5f * x * (1.f + erff(x * 0.70710678118654752440f));
}

struct PrepArgs {
    const float *Wq, *Wk, *Wv, *Wo, *W1, *W2, *bq, *bk, *bv;
    bf16_t *wqkvT, *woT, *w1T, *w2T;
    float *bqkv;
};

// prep body: 1731 blocks — 3 bias + 576 (Wq,Wk,Wv,Wo) + 576 (W1) + 576 (W2).
// PAD=67 (odd): transpose-read bank stride 12 mod 32.
__device__ __forceinline__ void prep_body(int bidx, int tid, const PrepArgs& pa, void* lds) {
    if (bidx < 3) {
        int i = bidx * 256 + tid;
        if (i < D_) {
            pa.bqkv[i] = pa.bq[i]; pa.bqkv[D_ + i] = pa.bk[i]; pa.bqkv[2*D_ + i] = pa.bv[i];
        }
        return;
    }
    int t = bidx - 3;
    const float* W; bf16_t* BT; int K, N;
    if (t < 576) {
        int seg = t / 144; t -= seg * 144;
        K = D_; N = D_;
        W  = (seg == 0 ? pa.Wq : seg == 1 ? pa.Wk : seg == 2 ? pa.Wv : pa.Wo);
        BT = (seg == 3 ? pa.woT : pa.wqkvT + (size_t)seg * 768 * D_);
    } else if (t < 1152) { t -= 576;  W = pa.W1; BT = pa.w1T; K = D_; N = F_; }
    else                 { t -= 1152; W = pa.W2; BT = pa.w2T; K = F_; N = D_; }
    const int kt = K / 64;
    const int k0 = (t % kt) * 64, n0 = (t / kt) * 64;

    bf16_t (*s)[67] = (bf16_t(*)[67])lds;
    int kr = tid >> 4, nc = (tid & 15) * 4;
    #pragma unroll
    for (int i = 0; i < 4; ++i) {
        float4 v = *(const float4*)(W + (size_t)(k0 + kr + i*16) * N + n0 + nc);
        s[kr + i*16][nc]     = (bf16_t)v.x;
        s[kr + i*16][nc + 1] = (bf16_t)v.y;
        s[kr + i*16][nc + 2] = (bf16_t)v.z;
        s[kr + i*16][nc + 3] = (bf16_t)v.w;
    }
    __syncthreads();
    int nr = tid >> 3, kc = (tid & 7) * 8;
    #pragma unroll
    for (int i = 0; i < 2; ++i) {
        bf16x8 o;
        #pragma unroll
        for (int j = 0; j < 8; ++j) o[j] = s[kc + j][nr + i*32];
        *(bf16x8*)(BT + (size_t)(n0 + nr + i*32) * K + k0 + kc) = o;
    }
}

// ---------------- elementwise: h = bf16(x + pos) ----------------
__global__ __launch_bounds__(256) void k_addpos(const float4* __restrict__ x,
                                                const float4* __restrict__ pos,
                                                bf16x4* __restrict__ h,
                                                int n4, int ld4) {
    int i = blockIdx.x * 256 + threadIdx.x;
    if (i < n4) {
        float4 a = x[i];
        float4 p = pos[i % ld4];
        bf16x4 o;
        o[0] = (bf16_t)(a.x + p.x); o[1] = (bf16_t)(a.y + p.y);
        o[2] = (bf16_t)(a.z + p.z); o[3] = (bf16_t)(a.w + p.w);
        h[i] = o;
    }
}

// standalone prep (layer 0 prologue)
__global__ __launch_bounds__(256) void k_prep(PrepArgs pa) {
    __shared__ bf16_t s[64][67];
    prep_body(blockIdx.x, threadIdx.x, pa, (void*)s);
}

// ---------------- LayerNorm: one wave per row, bf16 input ----------------
template<bool BF16OUT>
__global__ __launch_bounds__(256) void k_ln(const bf16_t* __restrict__ x,
                                            const float* __restrict__ g,
                                            const float* __restrict__ bsh,
                                            void* __restrict__ out) {
    int wid = threadIdx.x >> 6, lane = threadIdx.x & 63;
    size_t row = (size_t)blockIdx.x * 4 + wid;
    const bf16x4* xr = (const bf16x4*)(x + row * D_);
    float vv[12];
    float s = 0.f, sq = 0.f;
    #pragma unroll
    for (int i = 0; i < 3; ++i) {
        bf16x4 v4 = xr[i*64 + lane];
        #pragma unroll
        for (int j = 0; j < 4; ++j) {
            float f = (float)v4[j];
            vv[i*4 + j] = f; s += f; sq += f*f;
        }
    }
    #pragma unroll
    for (int o = 1; o < 64; o <<= 1) { s += __shfl_xor(s, o); sq += __shfl_xor(sq, o); }
    float mean = s * (1.f/768.f);
    float var  = sq * (1.f/768.f) - mean*mean;
    float rstd = rsqrtf(var + 1e-6f);
    const float4* g4 = (const float4*)g;
    const float4* b4 = (const float4*)bsh;
    #pragma unroll
    for (int i = 0; i < 3; ++i) {
        float4 gg = g4[i*64 + lane], bb = b4[i*64 + lane];
        float r0 = (vv[i*4+0] - mean)*rstd*gg.x + bb.x;
        float r1 = (vv[i*4+1] - mean)*rstd*gg.y + bb.y;
        float r2 = (vv[i*4+2] - mean)*rstd*gg.z + bb.z;
        float r3 = (vv[i*4+3] - mean)*rstd*gg.w + bb.w;
        if (BF16OUT) {
            bf16x4 o4; o4[0]=(bf16_t)r0; o4[1]=(bf16_t)r1; o4[2]=(bf16_t)r2; o4[3]=(bf16_t)r3;
            ((bf16x4*)((bf16_t*)out + row * D_))[i*64 + lane] = o4;
        } else {
            float4 r; r.x=r0; r.y=r1; r.z=r2; r.w=r3;
            ((float4*)out)[row * (D_/4) + i*64 + lane] = r;
        }
    }
}

// ---------------- GEMM 128x128 (m97-pure, 4 blocks/CU) + optional prep piggyback -------
// single-buffer LDS, 2x __syncthreads, no fences. T2 swizzle, XCD swizzle (over nwg).
// EPI 0: bias->bf16 wide.  EPI 1: +gelu wide.  EPI 2: bias+resid->bf16 wide f32-LDS.
// PREP: blocks [nwg, nwg+NPREP_) run prep_body for the NEXT layer's weights.
template<int EPI, bool PREP>
__global__ __launch_bounds__(256, 4) void k_gemm_bt(
        const bf16_t* __restrict__ A, const bf16_t* __restrict__ BT,
        const float* __restrict__ bias, const bf16_t* __restrict__ resid,
        void* __restrict__ Cout, int K, int N, int NB, int nwg, PrepArgs pa) {
    __shared__ bf16_t LDS_[2][128 * 64];   // 32KB total, contiguous
    bf16_t* As = LDS_[0];
    bf16_t* Bs = LDS_[1];

    const int tid = threadIdx.x, lane = tid & 63, wid = tid >> 6;

    if (PREP && (int)blockIdx.x >= nwg) {
        prep_body((int)blockIdx.x - nwg, tid, pa, (void*)LDS_);
        return;
    }

    const int g = lane >> 4, fr = lane & 15;
    const int wm = (wid >> 1) * 64, wn = (wid & 1) * 64;

    int orig = (int)blockIdx.x;
    int qq = nwg >> 3, rr = nwg & 7;
    int xcd = orig & 7, idx = orig >> 3;
    int wg = (xcd < rr ? xcd * (qq + 1) : rr * (qq + 1) + (xcd - rr) * qq) + idx;
    int bx = wg / NB, by = wg - bx * NB;
    const int gm0 = bx * 128, gn0 = by * 128;

    const int srl = lane >> 3;
    const int sc = ((lane & 7) ^ srl) * 8;

    f32x4 acc[4][4];
    #pragma unroll
    for (int i = 0; i < 4; ++i)
        #pragma unroll
        for (int j = 0; j < 4; ++j) acc[i][j] = (f32x4){0.f, 0.f, 0.f, 0.f};

    const bf16_t* a_src = A  + (size_t)(gm0 + wid * 32 + srl) * K + sc;
    const bf16_t* b_src = BT + (size_t)(gn0 + wid * 32 + srl) * K + sc;

    const int NT = K >> 6;
    for (int t = 0; t < NT; ++t) {
        const int k0 = t * 64;
        __syncthreads();
        #pragma unroll
        for (int i = 0; i < 4; ++i) {
            __builtin_amdgcn_global_load_lds(GPTR(a_src + (size_t)(i * 8) * K + k0),
                                             LPTR(&As[(wid * 32 + i * 8) * 64]), 16, 0, 0);
            __builtin_amdgcn_global_load_lds(GPTR(b_src + (size_t)(i * 8) * K + k0),
                                             LPTR(&Bs[(wid * 32 + i * 8) * 64]), 16, 0, 0);
        }
        __syncthreads();

        bf16x8 af[4][2], bf[4][2];
        #pragma unroll
        for (int mi = 0; mi < 4; ++mi) {
            const int row = wm + mi * 16 + fr;
            #pragma unroll
            for (int kc = 0; kc < 2; ++kc)
                af[mi][kc] = *(const bf16x8*)&As[row * 64 + (((kc * 4 + g) ^ (row & 7)) * 8)];
        }
        #pragma unroll
        for (int ni = 0; ni < 4; ++ni) {
            const int row = wn + ni * 16 + fr;
            #pragma unroll
            for (int kc = 0; kc < 2; ++kc)
                bf[ni][kc] = *(const bf16x8*)&Bs[row * 64 + (((kc * 4 + g) ^ (row & 7)) * 8)];
        }
        #pragma unroll
        for (int kc = 0; kc < 2; ++kc)
            #pragma unroll
            for (int mi = 0; mi < 4; ++mi)
                #pragma unroll
                for (int ni = 0; ni < 4; ++ni)
                    acc[mi][ni] = __builtin_amdgcn_mfma_f32_16x16x32_bf16(
                        af[mi][kc], bf[ni][kc], acc[mi][ni], 0, 0, 0);
    }

    if (EPI == 2) {
        // wide epilogue, f32 precision: two halves of 64 rows through f32 LDS [64][128].
        float* Cf = (float*)&LDS_[0][0];     // 32 KB
        #pragma unroll
        for (int h = 0; h < 2; ++h) {
            __syncthreads();
            if ((wid >> 1) == h) {
                #pragma unroll
                for (int mi = 0; mi < 4; ++mi)
                    #pragma unroll
                    for (int ni = 0; ni < 4; ++ni) {
                        const int c = wn + ni * 16 + fr;
                        const float bval = bias[gn0 + c];
                        #pragma unroll
                        for (int v = 0; v < 4; ++v) {
                            const int rl = mi * 16 + g * 4 + v;   // 0..63
                            Cf[rl * 128 + (((c >> 2) ^ (rl & 7)) << 2) + (c & 3)] =
                                acc[mi][ni][v] + bval;
                        }
                    }
            }
            __syncthreads();
            #pragma unroll
            for (int pass = 0; pass < 4; ++pass) {
                const int rl = pass * 16 + (tid >> 4);
                const int lc0 = (tid & 15) * 2;
                const int s2 = rl & 7;
                f32x4 lo = *(const f32x4*)&Cf[rl * 128 + ((lc0 ^ s2) << 2)];
                f32x4 hi = *(const f32x4*)&Cf[rl * 128 + (((lc0 + 1) ^ s2) << 2)];
                const int grow = gm0 + h * 64 + rl;
                if (grow < M_) {
                    const size_t base = (size_t)grow * N + gn0 + (tid & 15) * 8;
                    bf16x8 res = *(const bf16x8*)(resid + base);
                    bf16x8 o;
                    o[0] = (bf16_t)(lo[0] + (float)res[0]);
                    o[1] = (bf16_t)(lo[1] + (float)res[1]);
                    o[2] = (bf16_t)(lo[2] + (float)res[2]);
                    o[3] = (bf16_t)(lo[3] + (float)res[3]);
                    o[4] = (bf16_t)(hi[0] + (float)res[4]);
                    o[5] = (bf16_t)(hi[1] + (float)res[5]);
                    o[6] = (bf16_t)(hi[2] + (float)res[6]);
                    o[7] = (bf16_t)(hi[3] + (float)res[7]);
                    *(bf16x8*)((bf16_t*)Cout + base) = o;
                }
            }
        }
    } else {
        // wide epilogue: bf16 LDS transpose (32KB = [128][128] bf16, chunk-XOR swizzled)
        __syncthreads();
        bf16_t* Cs = &LDS_[0][0];
        #pragma unroll
        for (int mi = 0; mi < 4; ++mi)
            #pragma unroll
            for (int ni = 0; ni < 4; ++ni) {
                const int col = wn + ni * 16 + fr;
                const float bval = bias[gn0 + col];
                const int ch = col >> 3, co = col & 7;
                #pragma unroll
                for (int v = 0; v < 4; ++v) {
                    const int row = wm + mi * 16 + g * 4 + v;
                    float val = acc[mi][ni][v] + bval;
                    if (EPI == 1) val = gelu_f(val);
                    Cs[row * 128 + ((ch ^ (row & 7)) << 3) + co] = (bf16_t)val;
                }
            }
        __syncthreads();
        #pragma unroll
        for (int p = 0; p < 8; ++p) {
            const int row = p * 16 + (tid >> 4);
            const int ch  = tid & 15;
            const int grow = gm0 + row;
            bf16x8 cv = *(const bf16x8*)&Cs[row * 128 + ((ch ^ (row & 7)) << 3)];
            if (grow < M_)
                *(bf16x8*)((bf16_t*)Cout + (size_t)grow * N + gn0 + ch * 8) = cv;
        }
    }
}

// ---------------- Attention: one block per (b,h), full-row softmax ----------------
__global__ __launch_bounds__(256) void k_attn(const bf16_t* __restrict__ qkv,
                                              bf16_t* __restrict__ out) {
    __shared__ bf16_t VT[64][232];
    __shared__ bf16_t P[4][16][232];
    int tid = threadIdx.x, lane = tid & 63, wid = tid >> 6;
    int b = blockIdx.x / H_, hh = blockIdx.x % H_;
    const size_t base = (size_t)b * L_ * 2304 + hh * 64;

    for (int r = tid >> 3; r < L_; r += 32) {
        int cg = (tid & 7) * 8;
        bf16x8 vv = *(const bf16x8*)(qkv + base + (size_t)r * 2304 + 1536 + cg);
        #pragma unroll
        for (int j = 0; j < 8; ++j) VT[cg + j][r] = vv[j];
    }
    for (int i = tid; i < 64 * 35; i += 256) VT[i / 35][197 + i % 35] = (bf16_t)0.f;
    {
        int r = lane & 15, c0 = 208 + (lane >> 4) * 4;
        #pragma unroll
        for (int j = 0; j < 4; ++j) P[wid][r][c0 + j] = (bf16_t)0.f;
    }
    __syncthreads();

    for (int s = wid; s < 13; s += 4) {
        int q0 = s * 16;
        int qr = q0 + (lane & 15); if (qr > L_ - 1) qr = L_ - 1;
        bf16x8 qf[2];
        #pragma unroll
        for (int kk = 0; kk < 2; ++kk)
            qf[kk] = *(const bf16x8*)(qkv + base + (size_t)qr * 2304 + kk * 32 + (lane >> 4) * 8);

        f32x4 sacc[13];
        #pragma unroll
        for (int nb = 0; nb < 13; ++nb) { f32x4 z = {0.f,0.f,0.f,0.f}; sacc[nb] = z; }
        #pragma unroll
        for (int nb = 0; nb < 13; ++nb) {
            int lk = nb * 16 + (lane & 15); if (lk > L_ - 1) lk = L_ - 1;
            #pragma unroll
            for (int kk = 0; kk < 2; ++kk) {
                bf16x8 kf = *(const bf16x8*)(qkv + base + (size_t)lk * 2304 + D_ + kk * 32 + (lane >> 4) * 8);
                sacc[nb] = __builtin_amdgcn_mfma_f32_16x16x32_bf16(qf[kk], kf, sacc[nb], 0, 0, 0);
            }
        }

        float mx[4] = {-1e30f, -1e30f, -1e30f, -1e30f};
        float pv[13][4];
        #pragma unroll
        for (int nb = 0; nb < 13; ++nb) {
            bool valid = (nb * 16 + (lane & 15)) < L_;
            #pragma unroll
            for (int v = 0; v < 4; ++v) {
                float sv = valid ? sacc[nb][v] * 0.125f : -1e30f;
                pv[nb][v] = sv;
                mx[v] = fmaxf(mx[v], sv);
            }
        }
        #pragma unroll
        for (int o = 1; o < 16; o <<= 1) {
            #pragma unroll
            for (int v = 0; v < 4; ++v) mx[v] = fmaxf(mx[v], __shfl_xor(mx[v], o));
        }
        float sum[4] = {0.f, 0.f, 0.f, 0.f};
        #pragma unroll
        for (int nb = 0; nb < 13; ++nb) {
            bool valid = (nb * 16 + (lane & 15)) < L_;
            #pragma unroll
            for (int v = 0; v < 4; ++v) {
                float e2 = valid ? __expf(pv[nb][v] - mx[v]) : 0.f;
                pv[nb][v] = e2; sum[v] += e2;
            }
        }
        #pragma unroll
        for (int o = 1; o < 16; o <<= 1) {
            #pragma unroll
            for (int v = 0; v < 4; ++v) sum[v] += __shfl_xor(sum[v], o);
        }

        #pragma unroll
        for (int nb = 0; nb < 13; ++nb)
            #pragma unroll
            for (int v = 0; v < 4; ++v)
                P[wid][(lane >> 4) * 4 + v][nb * 16 + (lane & 15)] = (bf16_t)pv[nb][v];
        asm volatile("s_waitcnt lgkmcnt(0)" ::: "memory");

        f32x4 oacc[4];
        #pragma unroll
        for (int nb = 0; nb < 4; ++nb) { f32x4 z = {0.f,0.f,0.f,0.f}; oacc[nb] = z; }
        #pragma unroll
        for (int kk = 0; kk < 7; ++kk) {
            bf16x8 pf = *(const bf16x8*)&P[wid][lane & 15][kk * 32 + (lane >> 4) * 8];
            #pragma unroll
            for (int nb = 0; nb < 4; ++nb) {
                bf16x8 vf = *(const bf16x8*)&VT[nb * 16 + (lane & 15)][kk * 32 + (lane >> 4) * 8];
                oacc[nb] = __builtin_amdgcn_mfma_f32_16x16x32_bf16(pf, vf, oacc[nb], 0, 0, 0);
            }
        }

        float rs[4];
        #pragma unroll
        for (int v = 0; v < 4; ++v) rs[v] = 1.f / sum[v];
        #pragma unroll
        for (int nb = 0; nb < 4; ++nb)
            #pragma unroll
            for (int v = 0; v < 4; ++v) {
                int r = q0 + (lane >> 4) * 4 + v;
                if (r < L_)
                    out[((size_t)b * L_ + r) * D_ + hh * 64 + nb * 16 + (lane & 15)] =
                        (bf16_t)(oacc[nb][v] * rs[v]);
            }
    }
}

// ---------------- host orchestration ----------------
extern "C" void kernel_launch(void* const* d_in, const int* in_sizes, int n_in,
                              void* d_out, int out_size, void* d_ws, size_t ws_size,
                              hipStream_t stream) {
    const float* x     = (const float*)d_in[0];
    const float* pos   = (const float*)d_in[1];
    const float* ln1_g = (const float*)d_in[2];
    const float* ln1_b = (const float*)d_in[3];
    const float* Wq    = (const float*)d_in[4];
    const float* bq    = (const float*)d_in[5];
    const float* Wk    = (const float*)d_in[6];
    const float* bk    = (const float*)d_in[7];
    const float* Wv    = (const float*)d_in[8];
    const float* bv    = (const float*)d_in[9];
    const float* Wo    = (const float*)d_in[10];
    const float* bo    = (const float*)d_in[11];
    const float* ln2_g = (const float*)d_in[12];
    const float* ln2_b = (const float*)d_in[13];
    const float* W1    = (const float*)d_in[14];
    const float* b1    = (const float*)d_in[15];
    const float* W2    = (const float*)d_in[16];
    const float* b2    = (const float*)d_in[17];
    const float* lnf_g = (const float*)d_in[18];
    const float* lnf_b = (const float*)d_in[19];

    char* wsp = (char*)d_ws;
    size_t off = 0;
    auto alloc = [&](size_t bytes) -> void* {
        void* r = wsp + off;
        off += (bytes + 255) & ~(size_t)255;
        return r;
    };
    bf16_t* h     = (bf16_t*)alloc((size_t)M_ * D_ * 2);
    bf16_t* y     = (bf16_t*)alloc((size_t)MPAD_ * D_ * 2);
    bf16_t* qkv   = (bf16_t*)alloc((size_t)M_ * 2304 * 2);
    bf16_t* attn  = (bf16_t*)alloc((size_t)MPAD_ * D_ * 2);
    bf16_t* u     = (bf16_t*)alloc((size_t)MPAD_ * F_ * 2);
    bf16_t* wqkvT[2]; bf16_t* woT[2]; bf16_t* w1T[2]; bf16_t* w2T[2]; float* bqkv[2];
    for (int p = 0; p < 2; ++p) {
        wqkvT[p] = (bf16_t*)alloc((size_t)2304 * D_ * 2);
        woT[p]   = (bf16_t*)alloc((size_t)D_ * D_ * 2);
        w1T[p]   = (bf16_t*)alloc((size_t)F_ * D_ * 2);
        w2T[p]   = (bf16_t*)alloc((size_t)D_ * F_ * 2);
        bqkv[p]  = (float*) alloc(2304 * 4);
    }
    (void)ws_size; (void)in_sizes; (void)n_in; (void)out_size;

    auto mkprep = [&](int l) -> PrepArgs {
        int p = l & 1;
        PrepArgs pa;
        pa.Wq = Wq + (size_t)l * D_ * D_; pa.Wk = Wk + (size_t)l * D_ * D_;
        pa.Wv = Wv + (size_t)l * D_ * D_; pa.Wo = Wo + (size_t)l * D_ * D_;
        pa.W1 = W1 + (size_t)l * D_ * F_; pa.W2 = W2 + (size_t)l * F_ * D_;
        pa.bq = bq + l * D_; pa.bk = bk + l * D_; pa.bv = bv + l * D_;
        pa.wqkvT = wqkvT[p]; pa.woT = woT[p]; pa.w1T = w1T[p]; pa.w2T = w2T[p];
        pa.bqkv = bqkv[p];
        return pa;
    };
    PrepArgs nopa = {};

    {
        int n4 = M_ * D_ / 4;
        k_addpos<<<(n4 + 255) / 256, 256, 0, stream>>>((const float4*)x, (const float4*)pos,
                                                       (bf16x4*)h, n4, L_ * D_ / 4);
    }
    k_prep<<<NPREP_, 256, 0, stream>>>(mkprep(0));

    for (int l = 0; l < NL_; ++l) {
        const int p = l & 1;
        k_ln<true><<<M_ / 4, 256, 0, stream>>>(h, ln1_g + l * D_, ln1_b + l * D_, y);
        k_gemm_bt<0, false><<<dim3(99 * 18), 256, 0, stream>>>(
            y, wqkvT[p], bqkv[p], nullptr, qkv, D_, 2304, 18, 99 * 18, nopa);
        k_attn<<<B_ * H_, 256, 0, stream>>>(qkv, attn);
        k_gemm_bt<2, false><<<dim3(99 * 6), 256, 0, stream>>>(
            attn, woT[p], bo + l * D_, h, h, D_, D_, 6, 99 * 6, nopa);
        k_ln<true><<<M_ / 4, 256, 0, stream>>>(h, ln2_g + l * D_, ln2_b + l * D_, y);
        if (l + 1 < NL_) {
            k_gemm_bt<1, true><<<dim3(99 * 24 + NPREP_), 256, 0, stream>>>(
                y, w1T[p], b1 + (size_t)l * F_, nullptr, u, D_, F_, 24, 99 * 24, mkprep(l + 1));
        } else {
            k_gemm_bt<1, false><<<dim3(99 * 24), 256, 0, stream>>>(
                y, w1T[p], b1 + (size_t)l * F_, nullptr, u, D_, F_, 24, 99 * 24, nopa);
        }
        k_gemm_bt<2, false><<<dim3(99 * 6), 256, 0, stream>>>(
            u, w2T[p], b2 + l * D_, h, h, F_, D_, 6, 99 * 6, nopa);
    }
    k_ln<false><<<M_ / 4, 256, 0, stream>>>(h, lnf_g, lnf_b, d_out);
}